// Round 9
// baseline (282.024 us; speedup 1.0000x reference)
//
#include <hip/hip_runtime.h>
#include <stdint.h>

// ---------------------------------------------------------------------------
// UserSpotConv: bipartite GCN aggregation.
//   user_out[u] = isd_u[u] * sum_{e: u_e=u} spot_x[s_e] * isd_s[s_e]
//   spot_out[s] = isd_s[s] * sum_{e: s_e=s} user_x[u_e] * isd_u[u_e]
// Round 9: r8's fused fscan lost 0.7x fill rate from halved wave count
// (3400 vs 7800 waves on a latency*MLP-bound random gather). Fix:
//  - ONE fscan2 launch covering BOTH directions (1094 blocks, ~8700 waves);
//    isd cycle broken by bdeg2 (hist-only, both bufs) before the converts.
//  - dst-major pass 3: wave owns dsts w,w+8,..; register-accumulate the whole
//    run; ONE plain coalesced store (block owns its rows -> no atomics).
//  - sorted[] holds ushort src only (17.5 KB LDS, fewer bank conflicts).
// Tier B = proven r8 sequential path if ws can't hold both bf16 tables.
// ---------------------------------------------------------------------------

#define NPB_LOG2 6
#define NPB 64             // destination nodes per bucket
#define MAXB 768           // max buckets per direction
#define PART_CHUNK 2048    // edges per block in part_kernel
#define BH_CHUNK 16384     // edges per block in bhist_kernel
#define SORT_CAP 8192      // r8 fscan: max edges per bucket (u32 stage)
#define SORT2_CAP 16384    // fscan2: max edges per bucket (ushort stage)

__device__ __forceinline__ ushort f2bf(float f) {
    uint32_t u = __float_as_uint(f);
    return (ushort)((u + 0x7fffu + ((u >> 16) & 1u)) >> 16);  // RNE
}

// Bucket-level histogram for BOTH directions in one pass.
__global__ __launch_bounds__(256) void bhist_kernel(
        const int* __restrict__ u, const int* __restrict__ s, int E,
        int nbu, int nbs, int* __restrict__ bd) {
    __shared__ int hist[2 * MAXB];
    const int tid = threadIdx.x;
    const int nb = nbu + nbs;
    const int beg = blockIdx.x * BH_CHUNK;
    const int end = min(beg + BH_CHUNK, E);
    for (int b = tid; b < nb; b += 256) hist[b] = 0;
    __syncthreads();
    for (int i = beg + tid; i < end; i += 256) {
        atomicAdd(&hist[u[i] >> NPB_LOG2], 1);
        atomicAdd(&hist[nbu + (s[i] >> NPB_LOG2)], 1);
    }
    __syncthreads();
    for (int b = tid; b < nb; b += 256) {
        int h = hist[b];
        if (h) atomicAdd(&bd[b], h);
    }
}

// Fused dual exclusive scan (block 0: u-buckets, block 1: s-buckets) that
// also initializes the part_kernel global cursors. n <= 1024 (MAXB=768).
__global__ __launch_bounds__(1024) void scan2_kernel(
        const int* __restrict__ bd, int nbu, int nbs,
        int* __restrict__ buoff, int* __restrict__ bsoff,
        int* __restrict__ gcu, int* __restrict__ gcs) {
    __shared__ int wsums[16];
    __shared__ int total;
    const int tid = threadIdx.x, lane = tid & 63, wid = tid >> 6;
    const int n   = blockIdx.x ? nbs : nbu;
    const int* in = blockIdx.x ? (bd + nbu) : bd;
    int* out = blockIdx.x ? bsoff : buoff;
    int* gc  = blockIdx.x ? gcs   : gcu;
    int v = (tid < n) ? in[tid] : 0;
    int x = v;
#pragma unroll
    for (int d = 1; d < 64; d <<= 1) {
        int t = __shfl_up(x, d);
        if (lane >= d) x += t;
    }
    if (lane == 63) wsums[wid] = x;
    __syncthreads();
    if (tid == 0) {
        int run = 0;
#pragma unroll
        for (int w = 0; w < 16; ++w) { int t = wsums[w]; wsums[w] = run; run += t; }
        total = run;
    }
    __syncthreads();
    int excl = wsums[wid] + (x - v);
    if (tid < n) { out[tid] = excl; gc[tid] = excl; }
    if (tid == 0) out[n] = total;
}

// xb row layout is PERMUTED: slot 2c holds col c, slot 2c+1 holds col c+64,
// so a lane's uint32 load at byte row*256+4*l yields cols (l, l+64).
__global__ void convert_kernel(const float* __restrict__ x, const float* __restrict__ isd,
                               ushort* __restrict__ xb, int n_rows) {
    int idx = blockIdx.x * blockDim.x + threadIdx.x;
    if (idx >= (n_rows << 6)) return;
    int row = idx >> 6, c = idx & 63;
    float w = isd[row];
    const float* xr = x + ((size_t)row << 7);
    ushort2 o;
    o.x = f2bf(xr[c] * w);
    o.y = f2bf(xr[c + 64] * w);
    *reinterpret_cast<ushort2*>(xb + ((size_t)row << 7) + 2 * c) = o;
}

// Partition edges into NPB-node buckets of the primary (destination) index.
// LDS-staged; element-parallel coalesced flush.
__global__ __launch_bounds__(256) void part_kernel(
        const int* __restrict__ prim, const int* __restrict__ sec, int E,
        int nb, int* __restrict__ gcur, uint32_t* __restrict__ out) {
    __shared__ int hist[MAXB];
    __shared__ int loff[MAXB];
    __shared__ int gbase[MAXB];
    __shared__ int cur[MAXB];
    __shared__ int wsum[4];
    __shared__ uint32_t sbuf[PART_CHUNK];
    const int tid = threadIdx.x;
    const int lane = tid & 63;
    const int wid = tid >> 6;
    const int beg = blockIdx.x * PART_CHUNK;
    const int end = min(beg + PART_CHUNK, E);
    const int cnt_total = end - beg;
    for (int b = tid; b < nb; b += 256) hist[b] = 0;
    __syncthreads();
    for (int i = beg + tid; i < end; i += 256)
        atomicAdd(&hist[prim[i] >> NPB_LOG2], 1);
    __syncthreads();
    {
        int b0 = tid * 3;
        int h0 = (b0 + 0 < nb) ? hist[b0 + 0] : 0;
        int h1 = (b0 + 1 < nb) ? hist[b0 + 1] : 0;
        int h2 = (b0 + 2 < nb) ? hist[b0 + 2] : 0;
        int tsum = h0 + h1 + h2;
        int x = tsum;
#pragma unroll
        for (int d = 1; d < 64; d <<= 1) {
            int t = __shfl_up(x, d);
            if (lane >= d) x += t;
        }
        if (lane == 63) wsum[wid] = x;
        __syncthreads();
        if (tid == 0) {
            int run = 0;
#pragma unroll
            for (int w = 0; w < 4; ++w) { int t = wsum[w]; wsum[w] = run; run += t; }
        }
        __syncthreads();
        int base = wsum[wid] + (x - tsum);
        if (b0 + 0 < nb) loff[b0 + 0] = base;
        if (b0 + 1 < nb) loff[b0 + 1] = base + h0;
        if (b0 + 2 < nb) loff[b0 + 2] = base + h0 + h1;
    }
    __syncthreads();
    for (int b = tid; b < nb; b += 256) {
        cur[b] = loff[b];
        int c = hist[b];
        gbase[b] = c > 0 ? atomicAdd(&gcur[b], c) : 0;
    }
    __syncthreads();
    for (int i = beg + tid; i < end; i += 256) {
        int p = prim[i], s = sec[i];
        int b = p >> NPB_LOG2;
        int l = atomicAdd(&cur[b], 1);
        sbuf[l] = ((uint32_t)p << 16) | (uint32_t)s;
    }
    __syncthreads();
    for (int k = tid; k < cnt_total; k += 256) {
        uint32_t p = sbuf[k];
        int b = (int)(p >> (16 + NPB_LOG2));
        out[gbase[b] + (k - loff[b])] = p;
    }
}

// Histogram-only pass over BOTH bucketed edge buffers: isd = rsqrt(deg).
__global__ __launch_bounds__(256) void bdeg2_kernel(
        const uint32_t* __restrict__ bufU, const uint32_t* __restrict__ bufS,
        const int* __restrict__ buoff, const int* __restrict__ bsoff, int nbu,
        float* __restrict__ isd_u, float* __restrict__ isd_s, int N, int M) {
    __shared__ int hist[NPB];
    const int tid = threadIdx.x;
    const int b = blockIdx.x;
    const uint32_t* buf; const int* boff; float* isd; int n_rows; int bb;
    if (b < nbu) { buf = bufU; boff = buoff; isd = isd_u; n_rows = N; bb = b; }
    else         { buf = bufS; boff = bsoff; isd = isd_s; n_rows = M; bb = b - nbu; }
    const int jbeg = boff[bb];
    const int cnt = boff[bb + 1] - jbeg;
    if (tid < NPB) hist[tid] = 0;
    __syncthreads();
    for (int k = tid; k < cnt; k += 256)
        atomicAdd(&hist[(buf[jbeg + k] >> 16) & (NPB - 1)], 1);
    __syncthreads();
    if (tid < NPB) {
        int node = (bb << NPB_LOG2) + tid;
        if (node < n_rows) {
            int h = hist[tid];
            isd[node] = h > 0 ? rsqrtf((float)h) : 0.f;
        }
    }
}

// Combined both-direction fused sort+scan. One block per bucket (u buckets
// first, then s). Pass 1: LDS dst histogram. Pass 2: scatter ushort src
// dst-sorted into LDS. Pass 3: dst-major — wave w owns local dsts w,w+8,..,
// register-accumulates the dst's whole run, multiplies isd, ONE plain
// coalesced store (block exclusively owns its 64 output rows -> no atomics;
// deg-0 rows covered by the d_out memset). Oversize buckets (> SORT2_CAP,
// statistically absent) fall back to unsorted run-scan with atomics.
__global__ __launch_bounds__(512) void fscan2_kernel(
        const ushort* __restrict__ xbs, const ushort* __restrict__ xbu,
        const uint32_t* __restrict__ bufU, const uint32_t* __restrict__ bufS,
        const int* __restrict__ buoff, const int* __restrict__ bsoff, int nbu,
        float* __restrict__ user_out, float* __restrict__ spot_out) {
    __shared__ ushort srt[SORT2_CAP];
    __shared__ int hist[NPB];
    __shared__ int scur[NPB];
    __shared__ float isdl[NPB];
    const int tid = threadIdx.x;
    const int b = blockIdx.x;
    const ushort* xb; const uint32_t* buf; const int* boff; float* out; int bb;
    if (b < nbu) { xb = xbs; buf = bufU; boff = buoff; out = user_out; bb = b; }
    else         { xb = xbu; buf = bufS; boff = bsoff; out = spot_out; bb = b - nbu; }
    const int jbeg = boff[bb];
    const int cnt = boff[bb + 1] - jbeg;
    if (cnt <= 0) return;                       // memset covers all-zero rows
    const bool fits = (cnt <= SORT2_CAP);
    if (tid < NPB) hist[tid] = 0;
    __syncthreads();
    for (int k = tid; k < cnt; k += 512)
        atomicAdd(&hist[(buf[jbeg + k] >> 16) & (NPB - 1)], 1);
    __syncthreads();
    if (tid < NPB) {
        int h = hist[tid];
        int x = h;
#pragma unroll
        for (int d = 1; d < 64; d <<= 1) {
            int t = __shfl_up(x, d);
            if (tid >= d) x += t;
        }
        scur[tid] = x - h;                      // exclusive base
        isdl[tid] = h > 0 ? rsqrtf((float)h) : 0.f;
    }
    __syncthreads();
    if (fits) {
        for (int k = tid; k < cnt; k += 512) {
            uint32_t p = buf[jbeg + k];
            int slot = atomicAdd(&scur[(p >> 16) & (NPB - 1)], 1);
            srt[slot] = (ushort)p;
        }
    }
    __syncthreads();
    const int wid = tid >> 6, lane = tid & 63;
    const int rowbase = bb << NPB_LOG2;

#define ROWX(sv) (*reinterpret_cast<const uint32_t*>( \
        xb + (((size_t)(sv)) << 7) + (lane << 1)))
#define UPX(rv) __uint_as_float((rv) << 16)
#define UPY(rv) __uint_as_float((rv) & 0xffff0000u)

    if (fits) {
        for (int ld = wid; ld < NPB; ld += 8) {
            const int deg = hist[ld];
            if (!deg) continue;                  // memset covers deg-0 rows
            const int off0 = scur[ld] - deg;     // scur is now end offset
            const float w = isdl[ld];
            float ax = 0.f, ay = 0.f;
            int j = 0;
            if (deg >= 16) {
                ushort c0 = srt[off0+0], c1 = srt[off0+1], c2 = srt[off0+2], c3 = srt[off0+3],
                       c4 = srt[off0+4], c5 = srt[off0+5], c6 = srt[off0+6], c7 = srt[off0+7];
                uint32_t r0 = ROWX(c0), r1 = ROWX(c1), r2 = ROWX(c2), r3 = ROWX(c3),
                         r4 = ROWX(c4), r5 = ROWX(c5), r6 = ROWX(c6), r7 = ROWX(c7);
                for (j = 8; j + 8 <= deg; j += 8) {
                    const int q = off0 + j;
                    ushort n0 = srt[q+0], n1 = srt[q+1], n2 = srt[q+2], n3 = srt[q+3],
                           n4 = srt[q+4], n5 = srt[q+5], n6 = srt[q+6], n7 = srt[q+7];
                    uint32_t s0 = ROWX(n0), s1 = ROWX(n1), s2 = ROWX(n2), s3 = ROWX(n3),
                             s4 = ROWX(n4), s5 = ROWX(n5), s6 = ROWX(n6), s7 = ROWX(n7);
                    ax += ((UPX(r0) + UPX(r1)) + (UPX(r2) + UPX(r3)))
                        + ((UPX(r4) + UPX(r5)) + (UPX(r6) + UPX(r7)));
                    ay += ((UPY(r0) + UPY(r1)) + (UPY(r2) + UPY(r3)))
                        + ((UPY(r4) + UPY(r5)) + (UPY(r6) + UPY(r7)));
                    r0 = s0; r1 = s1; r2 = s2; r3 = s3;
                    r4 = s4; r5 = s5; r6 = s6; r7 = s7;
                }
                ax += ((UPX(r0) + UPX(r1)) + (UPX(r2) + UPX(r3)))
                    + ((UPX(r4) + UPX(r5)) + (UPX(r6) + UPX(r7)));
                ay += ((UPY(r0) + UPY(r1)) + (UPY(r2) + UPY(r3)))
                    + ((UPY(r4) + UPY(r5)) + (UPY(r6) + UPY(r7)));
            }
            for (; j < deg; ++j) {
                uint32_t r = ROWX(srt[off0 + j]);
                ax += UPX(r); ay += UPY(r);
            }
            const size_t ro = ((size_t)(rowbase + ld)) << 7;
            out[ro + lane]      = ax * w;
            out[ro + 64 + lane] = ay * w;
        }
    } else {
        // oversize: unsorted run-scan over global buf, atomic flush into
        // the memset-zeroed out rows (block still owns these rows, but
        // multiple waves may share a dst -> atomics required).
        const int cs = (cnt + 7) >> 3;
        const int beg = wid * cs;
        const int end = min(beg + cs, cnt);
        if (beg >= end) return;
        float ax = 0.f, ay = 0.f;
        int curd = (int)(buf[jbeg + beg] >> 16);
        for (int k = beg; k < end; ++k) {
            uint32_t p = buf[jbeg + k];
            int d_ = (int)(p >> 16);
            if (d_ != curd) {
                float w_ = isdl[curd & (NPB - 1)];
                unsafeAtomicAdd(out + ((size_t)curd << 7) + lane, ax * w_);
                unsafeAtomicAdd(out + ((size_t)curd << 7) + 64 + lane, ay * w_);
                ax = 0.f; ay = 0.f; curd = d_;
            }
            uint32_t r = ROWX((ushort)p);
            ax += UPX(r); ay += UPY(r);
        }
        float w_ = isdl[curd & (NPB - 1)];
        unsafeAtomicAdd(out + ((size_t)curd << 7) + lane, ax * w_);
        unsafeAtomicAdd(out + ((size_t)curd << 7) + 64 + lane, ay * w_);
    }
#undef UPY
#undef UPX
#undef ROWX
}

// ---- tier-B kernels (round-8 proven sequential path) ----------------------

__global__ __launch_bounds__(256) void bdeg_kernel(
        const uint32_t* __restrict__ buf, const int* __restrict__ boff,
        float* __restrict__ isd, int n_rows) {
    __shared__ int hist[NPB];
    const int tid = threadIdx.x;
    const int jbeg = boff[blockIdx.x];
    const int cnt = boff[blockIdx.x + 1] - jbeg;
    if (tid < NPB) hist[tid] = 0;
    __syncthreads();
    for (int k = tid; k < cnt; k += 256)
        atomicAdd(&hist[(buf[jbeg + k] >> 16) & (NPB - 1)], 1);
    __syncthreads();
    if (tid < NPB) {
        int node = (blockIdx.x << NPB_LOG2) + tid;
        if (node < n_rows) {
            int h = hist[tid];
            isd[node] = h > 0 ? rsqrtf((float)h) : 0.f;
        }
    }
}

__global__ __launch_bounds__(512) void fscan_kernel(
        const ushort* __restrict__ xb, const uint32_t* __restrict__ buf,
        const int* __restrict__ boff, float* __restrict__ isd_out,
        float* __restrict__ out, int n_rows) {
    __shared__ uint32_t sorted[SORT_CAP];
    __shared__ int hist[NPB];
    __shared__ int scur[NPB];
    __shared__ float isdl[NPB];
    const int tid = threadIdx.x;
    const int jbeg = boff[blockIdx.x];
    const int cnt = boff[blockIdx.x + 1] - jbeg;
    if (cnt <= 0) {
        if (tid < NPB) {
            int node = (blockIdx.x << NPB_LOG2) + tid;
            if (node < n_rows) isd_out[node] = 0.f;
        }
        return;
    }
    const bool fits = (cnt <= SORT_CAP);
    if (tid < NPB) hist[tid] = 0;
    __syncthreads();
    for (int k = tid; k < cnt; k += 512)
        atomicAdd(&hist[(buf[jbeg + k] >> 16) & (NPB - 1)], 1);
    __syncthreads();
    if (tid < NPB) {
        int h = hist[tid];
        int x = h;
#pragma unroll
        for (int d = 1; d < 64; d <<= 1) {
            int t = __shfl_up(x, d);
            if (tid >= d) x += t;
        }
        scur[tid] = x - h;
        float iv = h > 0 ? rsqrtf((float)h) : 0.f;
        isdl[tid] = iv;
        int node = (blockIdx.x << NPB_LOG2) + tid;
        if (node < n_rows) isd_out[node] = iv;
    }
    __syncthreads();
    if (fits) {
        for (int k = tid; k < cnt; k += 512) {
            uint32_t p = buf[jbeg + k];
            int slot = atomicAdd(&scur[(p >> 16) & (NPB - 1)], 1);
            sorted[slot] = p;
        }
    }
    __syncthreads();
    const int wid = tid >> 6, lane = tid & 63;
    const int cs = (cnt + 7) >> 3;
    const int beg = wid * cs;
    const int end = min(beg + cs, cnt);
    if (beg >= end) return;

#define QLD(i) (fits ? sorted[i] : buf[jbeg + (i)])
#define ROW(pv) (*reinterpret_cast<const uint32_t*>( \
        xb + (((size_t)((pv) & 0xffffu)) << 7) + (lane << 1)))
#define UPX(rv) __uint_as_float((rv) << 16)
#define UPY(rv) __uint_as_float((rv) & 0xffff0000u)
    float ax = 0.f, ay = 0.f;
    int curd = (int)(QLD(beg) >> 16);
    for (int k = beg; k < end; ++k) {
        uint32_t p = QLD(k);
        int d_ = (int)(p >> 16);
        if (d_ != curd) {
            float w_ = isdl[curd & (NPB - 1)];
            unsafeAtomicAdd(out + ((size_t)curd << 7) + lane, ax * w_);
            unsafeAtomicAdd(out + ((size_t)curd << 7) + 64 + lane, ay * w_);
            ax = 0.f; ay = 0.f; curd = d_;
        }
        uint32_t r = ROW(p);
        ax += UPX(r); ay += UPY(r);
    }
    float w_ = isdl[curd & (NPB - 1)];
    unsafeAtomicAdd(out + ((size_t)curd << 7) + lane, ax * w_);
    unsafeAtomicAdd(out + ((size_t)curd << 7) + 64 + lane, ay * w_);
#undef UPY
#undef UPX
#undef ROW
#undef QLD
}

// ---- minimal-ws fallback ---------------------------------------------------

__global__ void deg_kernel(const int* __restrict__ u, const int* __restrict__ s,
                           int E, int* __restrict__ udeg, int* __restrict__ sdeg) {
    int i = blockIdx.x * blockDim.x + threadIdx.x;
    if (i < E) {
        atomicAdd(&udeg[u[i]], 1);
        atomicAdd(&sdeg[s[i]], 1);
    }
}

__global__ void init_isd_kernel(const int* __restrict__ udeg, const int* __restrict__ sdeg,
                                float* __restrict__ isd_u, float* __restrict__ isd_s,
                                int n_user, int m_spot) {
    int i = blockIdx.x * blockDim.x + threadIdx.x;
    if (i < n_user) { int d = udeg[i]; isd_u[i] = d > 0 ? rsqrtf((float)d) : 0.f; }
    if (i < m_spot) { int d = sdeg[i]; isd_s[i] = d > 0 ? rsqrtf((float)d) : 0.f; }
}

__global__ __launch_bounds__(256) void scatter_kernel(const float* __restrict__ spot_x,
                                                      const float* __restrict__ user_x,
                                                      const int* __restrict__ u,
                                                      const int* __restrict__ s, int E,
                                                      const float* __restrict__ isd_u,
                                                      const float* __restrict__ isd_s,
                                                      float* __restrict__ spot_out,
                                                      float* __restrict__ user_out) {
    const int lane = threadIdx.x & 63;
    const int e = blockIdx.x * 4 + (threadIdx.x >> 6);
    if (e >= E) return;
    const int uu = u[e], ss = s[e];
    const float w = isd_u[uu] * isd_s[ss];
    const float2 sv = *reinterpret_cast<const float2*>(spot_x + (size_t)ss * 128 + lane * 2);
    const float2 uv = *reinterpret_cast<const float2*>(user_x + (size_t)uu * 128 + lane * 2);
    atomicAdd(&user_out[(size_t)uu * 128 + lane * 2 + 0], sv.x * w);
    atomicAdd(&user_out[(size_t)uu * 128 + lane * 2 + 1], sv.y * w);
    atomicAdd(&spot_out[(size_t)ss * 128 + lane * 2 + 0], uv.x * w);
    atomicAdd(&spot_out[(size_t)ss * 128 + lane * 2 + 1], uv.y * w);
}

static inline char* align256(char* p) {
    return (char*)(((uintptr_t)p + 255u) & ~(uintptr_t)255u);
}

extern "C" void kernel_launch(void* const* d_in, const int* in_sizes, int n_in,
                              void* d_out, int out_size, void* d_ws, size_t ws_size,
                              hipStream_t stream) {
    const float* spot_x = (const float*)d_in[0];
    const float* user_x = (const float*)d_in[1];
    const int*   edges  = (const int*)d_in[2];
    const int M = in_sizes[0] / 128;   // spots
    const int N = in_sizes[1] / 128;   // users
    const int E = in_sizes[2] / 2;
    const int* u = edges;        // user_spot[0]
    const int* s = edges + E;    // user_spot[1]
    float* spot_out = (float*)d_out;
    float* user_out = (float*)d_out + (size_t)M * 128;

    const int nbu = (N + NPB - 1) / NPB;
    const int nbs = (M + NPB - 1) / NPB;
    const int nm = (N > M) ? N : M;
    const int gpart = (E + PART_CHUNK - 1) / PART_CHUNK;

    // Common metadata layout (shared by tiers A and B).
    char* ws = (char*)d_ws;
    float*    isd_u = (float*)ws; ws = align256(ws + sizeof(float) * (size_t)N);
    float*    isd_s = (float*)ws; ws = align256(ws + sizeof(float) * (size_t)M);
    int*      bd    = (int*)ws;   ws = align256(ws + sizeof(int) * (size_t)(nbu + nbs));
    int*      buoff = (int*)ws;   ws = align256(ws + sizeof(int) * (size_t)(nbu + 1));
    int*      bsoff = (int*)ws;   ws = align256(ws + sizeof(int) * (size_t)(nbs + 1));
    int*      gcu   = (int*)ws;   ws = align256(ws + sizeof(int) * (size_t)nbu);
    int*      gcs   = (int*)ws;   ws = align256(ws + sizeof(int) * (size_t)nbs);
    uint32_t* bufU  = (uint32_t*)ws; ws = align256(ws + sizeof(uint32_t) * (size_t)E);
    uint32_t* bufS  = (uint32_t*)ws; ws = align256(ws + sizeof(uint32_t) * (size_t)E);
    ushort*   xbs   = (ushort*)ws;   // tier A: spot table (tier B: union slot)
    ushort*   xbu   = (ushort*)align256((char*)xbs + sizeof(ushort) * ((size_t)M * 128));
    size_t tierA_needed = (size_t)((char*)xbu - (char*)d_ws)
                        + sizeof(ushort) * ((size_t)N * 128);
    size_t tierB_needed = (size_t)((char*)xbs - (char*)d_ws)
                        + sizeof(ushort) * ((size_t)nm * 128);

    if (tierB_needed <= ws_size && nbu <= MAXB && nbs <= MAXB) {
        hipMemsetAsync(bd, 0, sizeof(int) * (size_t)(nbu + nbs), stream);
        hipMemsetAsync(d_out, 0, sizeof(float) * (size_t)out_size, stream);
        bhist_kernel<<<(E + BH_CHUNK - 1) / BH_CHUNK, 256, 0, stream>>>(
            u, s, E, nbu, nbs, bd);
        scan2_kernel<<<2, 1024, 0, stream>>>(bd, nbu, nbs, buoff, bsoff, gcu, gcs);
        part_kernel<<<gpart, 256, 0, stream>>>(u, s, E, nbu, gcu, bufU);
        part_kernel<<<gpart, 256, 0, stream>>>(s, u, E, nbs, gcs, bufS);
        if (tierA_needed <= ws_size) {
            // ---- tier A: both tables resident, single combined fscan2 ----
            bdeg2_kernel<<<nbu + nbs, 256, 0, stream>>>(
                bufU, bufS, buoff, bsoff, nbu, isd_u, isd_s, N, M);
            convert_kernel<<<((M << 6) + 255) / 256, 256, 0, stream>>>(spot_x, isd_s, xbs, M);
            convert_kernel<<<((N << 6) + 255) / 256, 256, 0, stream>>>(user_x, isd_u, xbu, N);
            fscan2_kernel<<<nbu + nbs, 512, 0, stream>>>(
                xbs, xbu, bufU, bufS, buoff, bsoff, nbu, user_out, spot_out);
        } else {
            // ---- tier B: round-8 proven sequential path (union table) ----
            ushort* xb = xbs;
            bdeg_kernel<<<nbs, 256, 0, stream>>>(bufS, bsoff, isd_s, M);
            convert_kernel<<<((M << 6) + 255) / 256, 256, 0, stream>>>(spot_x, isd_s, xb, M);
            fscan_kernel<<<nbu, 512, 0, stream>>>(xb, bufU, buoff, isd_u, user_out, N);
            convert_kernel<<<((N << 6) + 255) / 256, 256, 0, stream>>>(user_x, isd_u, xb, N);
            fscan_kernel<<<nbs, 512, 0, stream>>>(xb, bufS, bsoff, isd_s, spot_out, M);
        }
        return;
    }

    // ---- minimal-ws fallback: degree + atomic scatter ----------------------
    {
        char* w2 = (char*)d_ws;
        int*   udeg2  = (int*)w2;   w2 += sizeof(int) * (size_t)N;
        int*   sdeg2  = (int*)w2;   w2 += sizeof(int) * (size_t)M;
        float* isd_u2 = (float*)w2; w2 += sizeof(float) * (size_t)N;
        float* isd_s2 = (float*)w2; w2 += sizeof(float) * (size_t)M;
        if ((size_t)(w2 - (char*)d_ws) <= ws_size) {
            hipMemsetAsync(udeg2, 0, sizeof(int) * (size_t)(N + M), stream);
            deg_kernel<<<(E + 255) / 256, 256, 0, stream>>>(u, s, E, udeg2, sdeg2);
            init_isd_kernel<<<(nm + 255) / 256, 256, 0, stream>>>(
                udeg2, sdeg2, isd_u2, isd_s2, N, M);
            hipMemsetAsync(d_out, 0, sizeof(float) * (size_t)out_size, stream);
            scatter_kernel<<<((size_t)E + 3) / 4, 256, 0, stream>>>(
                spot_x, user_x, u, s, E, isd_u2, isd_s2, spot_out, user_out);
        }
    }
}